// Round 10
// baseline (300.733 us; speedup 1.0000x reference)
//
#include <hip/hip_runtime.h>
#include <hip/hip_bf16.h>

// TAttention: B=16, C=32, N=1024, T=128, R=10
//  K1 k_reduce_c : k[b,n,t] = sum_c alpha[c]*x[b,c,n,t]    (256 MB read, ~40us)
//  K2 kw_partial2: p_w[b][r][ch32][t] partials             (8 MB, fast)
//  K3 scores_softmax3: reduce partials + scores + softmax -> att bf16 (tiny)
//  K4 out_gemm7  : ZERO LDS, ZERO barriers. Wave owns 16 n x 128 t.
//     x: 8 independent float4/lane up front; att A-frags direct from L2
//     (512KB total, resident); 32 MFMA; 8 f32x4 stores. K1-style streaming.
// R2..R9 lesson: every LDS-staged K4 = ~15 GB/s/CU (phase-coupled blocks);
// K1-style uncoupled streams hit ~25 GB/s/CU. att is small enough to skip
// staging entirely -> make K4 structurally identical to K1.

#define B_ 16
#define C_ 32
#define N_ 1024
#define T_ 128
#define R_ 10

typedef __bf16 bf16x8 __attribute__((ext_vector_type(8)));
typedef float f32x4 __attribute__((ext_vector_type(4)));

// ---------------------------------------------------------------- kernel 1
__global__ __launch_bounds__(256) void k_reduce_c(const float* __restrict__ x,
                                                  const float* __restrict__ alpha,
                                                  float* __restrict__ k) {
    int bid = blockIdx.x;            // B * N/8 = 2048
    int b   = bid >> 7;
    int nc  = bid & 127;
    int tid = threadIdx.x;
    int nl  = tid >> 5;
    int lc  = tid & 31;
    int n   = nc * 8 + nl;
    const float4* xb = reinterpret_cast<const float4*>(
        x + ((size_t)(b * C_) * N_ + n) * T_) + lc;
    float4 acc = {0.f, 0.f, 0.f, 0.f};
    #pragma unroll 8
    for (int c = 0; c < C_; ++c) {
        float a = alpha[c];
        float4 v = xb[(size_t)c * (N_ * T_ / 4)];
        acc.x += a * v.x; acc.y += a * v.y; acc.z += a * v.z; acc.w += a * v.w;
    }
    reinterpret_cast<float4*>(k + ((size_t)b * N_ + n) * T_)[lc] = acc;
}

// ---------------------------------------------------------------- kernel 2
__global__ __launch_bounds__(128) void kw_partial2(const float* __restrict__ k,
                                                   const float* __restrict__ W1,
                                                   const float* __restrict__ W2,
                                                   float* __restrict__ p1,
                                                   float* __restrict__ p2) {
    __shared__ float wl[32][20];
    int bid = blockIdx.x;            // b*32 + ch
    int b   = bid >> 5;
    int ch  = bid & 31;
    int n0  = ch * 32;
    int t   = threadIdx.x;
    for (int i = t; i < 32 * 20; i += 128) {
        int nl = i & 31, q = i >> 5;
        wl[nl][q] = (q < 10) ? W1[q * N_ + n0 + nl] : W2[(q - 10) * N_ + n0 + nl];
    }
    __syncthreads();
    float a1[R_] = {}, a2[R_] = {};
    const float* kb = k + ((size_t)b * N_ + n0) * T_ + t;
    #pragma unroll 2
    for (int g = 0; g < 4; ++g) {
        float kv[8];
        #pragma unroll
        for (int j = 0; j < 8; ++j) kv[j] = kb[(g * 8 + j) * T_];
        #pragma unroll
        for (int j = 0; j < 8; ++j) {
            int nl = g * 8 + j;
            #pragma unroll
            for (int r = 0; r < R_; ++r) {
                a1[r] += kv[j] * wl[nl][r];
                a2[r] += kv[j] * wl[nl][10 + r];
            }
        }
    }
    #pragma unroll
    for (int r = 0; r < R_; ++r) {
        size_t o = (((size_t)b * R_ + r) * 32 + ch) * T_ + t;
        p1[o] = a1[r];
        p2[o] = a2[r];
    }
}

// ---------------------------------------------------------------- kernel 3
__global__ __launch_bounds__(128) void scores_softmax3(const float* __restrict__ p1,
                                                       const float* __restrict__ p2,
                                                       __bf16* __restrict__ att) {
    __shared__ __align__(16) float kw1s[T_][12];
    __shared__ __align__(16) float kw2s[T_][12];
    __shared__ float sc[T_][T_ + 1];
    int b = blockIdx.x;
    int t = threadIdx.x;
    #pragma unroll
    for (int r = 0; r < R_; ++r) {
        float s1 = 0.f, s2 = 0.f;
        const float* q1 = p1 + (((size_t)b * R_ + r) * 32) * T_ + t;
        const float* q2 = p2 + (((size_t)b * R_ + r) * 32) * T_ + t;
        #pragma unroll 4
        for (int ch = 0; ch < 32; ++ch) { s1 += q1[ch * T_]; s2 += q2[ch * T_]; }
        kw1s[t][r] = s1; kw2s[t][r] = s2;
    }
    __syncthreads();
    float myw[R_];
    #pragma unroll
    for (int r = 0; r < R_; ++r) myw[r] = kw1s[t][r];
    float mx = -1e30f;
    for (int s = 0; s < T_; ++s) {
        float wv[12];
        const float4* qr = reinterpret_cast<const float4*>(&kw2s[s][0]);
        #pragma unroll
        for (int q = 0; q < 3; ++q) *reinterpret_cast<float4*>(&wv[q * 4]) = qr[q];
        float v = 0.f;
        #pragma unroll
        for (int r = 0; r < R_; ++r) v += myw[r] * wv[r];
        sc[t][s] = v;
        mx = fmaxf(mx, v);
    }
    float sum = 0.f;
    for (int s = 0; s < T_; ++s) {
        float e = __expf(sc[t][s] - mx);
        sc[t][s] = e;
        sum += e;
    }
    float inv = 1.0f / sum;
    __bf16* arow = att + ((size_t)b * T_ + t) * T_;
    for (int s8 = 0; s8 < T_; s8 += 8) {
        bf16x8 hv;
        #pragma unroll
        for (int q = 0; q < 8; ++q) hv[q] = (__bf16)(sc[t][s8 + q] * inv);
        *reinterpret_cast<bf16x8*>(arow + s8) = hv;
    }
}

// ---------------------------------------------------------------- kernel 4
// grid = B*C*16 blocks x 256 thr (4 independent waves, NO barriers, NO LDS).
// wave owns n-rows [ng*64 + wave*16, +16) x all 128 t.
// per lane: 8 float4 x-loads (all in flight), 32 att frag loads (L2-hot),
// 32 MFMA (A=att row t, B=x row n; verified D map col->n row->t), 8 f32x4 st.
__global__ __launch_bounds__(256, 4) void out_gemm7(const float* __restrict__ x,
                                                    const __bf16* __restrict__ att,
                                                    float* __restrict__ out) {
    int bid = blockIdx.x;            // b*512 + c*16 + ng
    int ng  = bid & 15;
    int c   = (bid >> 4) & 31;
    int b   = bid >> 9;
    int tid = threadIdx.x;
    int wave = tid >> 6, lane = tid & 63;
    int r16 = lane & 15, g = lane >> 4;
    int n = ng * 64 + wave * 16 + r16;

    const float* xr = x + ((size_t)(b * C_ + c) * N_ + n) * T_ + g * 8;
    const char* ab  = (const char*)att + (size_t)b * (T_ * T_ * 2) +
                      r16 * 256 + g * 16;
    float* o = out + ((size_t)(b * C_ + c) * N_ + n) * T_ + g * 4;

    // all x loads issued up front: lane covers s = ks*32 + g*8 .. +7, ks=0..3
    float4 xf[8];
    #pragma unroll
    for (int q = 0; q < 8; ++q)
        xf[q] = *reinterpret_cast<const float4*>(xr + (q >> 1) * 32 + (q & 1) * 4);

    f32x4 acc[8] = {};
    #pragma unroll
    for (int ks = 0; ks < 4; ++ks) {
        float4 lo = xf[2 * ks], hi = xf[2 * ks + 1];
        bf16x8 bx = {(__bf16)lo.x, (__bf16)lo.y, (__bf16)lo.z, (__bf16)lo.w,
                     (__bf16)hi.x, (__bf16)hi.y, (__bf16)hi.z, (__bf16)hi.w};
        bf16x8 a[8];
        #pragma unroll
        for (int tt = 0; tt < 8; ++tt)   // att[t = tt*16 + r16][ks*32 + g*8 ..]
            a[tt] = *reinterpret_cast<const bf16x8*>(ab + tt * 4096 + ks * 64);
        #pragma unroll
        for (int tt = 0; tt < 8; ++tt)
            acc[tt] = __builtin_amdgcn_mfma_f32_16x16x32_bf16(a[tt], bx, acc[tt], 0, 0, 0);
    }
    // D: col = lane&15 -> n (in addr), row = g*4+j -> t; f32x4 along t
    #pragma unroll
    for (int tt = 0; tt < 8; ++tt)
        *reinterpret_cast<f32x4*>(o + tt * 16) = acc[tt];
}

// ----------------------------------------------------------------
extern "C" void kernel_launch(void* const* d_in, const int* in_sizes, int n_in,
                              void* d_out, int out_size, void* d_ws, size_t ws_size,
                              hipStream_t stream) {
    const float* x     = (const float*)d_in[0];
    const float* W1    = (const float*)d_in[1];
    const float* W2    = (const float*)d_in[2];
    const float* alpha = (const float*)d_in[3];
    float* out = (float*)d_out;

    const size_t KSZ = (size_t)B_ * N_ * T_;            // f32
    const size_t PSZ = (size_t)B_ * R_ * 32 * T_;       // f32
    float* k    = (float*)d_ws;
    float* p1   = k + KSZ;
    float* p2   = p1 + PSZ;
    __bf16* att = (__bf16*)(p2 + PSZ);                  // [b][t][s]

    k_reduce_c     <<<dim3(B_ * (N_ / 8)), dim3(256), 0, stream>>>(x, alpha, k);
    kw_partial2    <<<dim3(B_ * 32),       dim3(128), 0, stream>>>(k, W1, W2, p1, p2);
    scores_softmax3<<<dim3(B_),            dim3(128), 0, stream>>>(p1, p2, att);
    out_gemm7      <<<dim3(B_ * C_ * 16),  dim3(256), 0, stream>>>(x, att, out);
}

// Round 11
// 200.882 us; speedup vs baseline: 1.4971x; 1.4971x over previous
//
#include <hip/hip_runtime.h>
#include <hip/hip_bf16.h>

// TAttention: B=16, C=32, N=1024, T=128, R=10
//  K1 k_reduce_c : k[b,n,t] = sum_c alpha[c]*x[b,c,n,t]    (256 MB read, BW)
//  K2 kw_partial2: p_w[b][r][ch32][t] partials             (8 MB, fast)
//  K3 scores_softmax3: partial-reduce + scores + softmax -> att bf16 (tiny)
//  K4 out_gemm8  : R10 PMC verdict: all prior K4s were STORE-SCATTER-bound
//     (f32x4 at 512B stride = 16 lines/instr, ~2 TB/s). Fix: per-wave LDS
//     transpose epilogue -> 1KB contiguous store bursts. Wave owns 16 n-rows
//     x 128 t; bulk-staged x (dbuf regs->LDS); att staged once; reverse bid.

#define B_ 16
#define C_ 32
#define N_ 1024
#define T_ 128
#define R_ 10

typedef __bf16 bf16x8 __attribute__((ext_vector_type(8)));
typedef __bf16 bf16x4 __attribute__((ext_vector_type(4)));
typedef float f32x4 __attribute__((ext_vector_type(4)));

__device__ __forceinline__ void lds_barrier() {
    asm volatile("s_waitcnt lgkmcnt(0)" ::: "memory");
    __builtin_amdgcn_s_barrier();
    asm volatile("" ::: "memory");
}

// ---------------------------------------------------------------- kernel 1
__global__ __launch_bounds__(256) void k_reduce_c(const float* __restrict__ x,
                                                  const float* __restrict__ alpha,
                                                  float* __restrict__ k) {
    int bid = blockIdx.x;            // B * N/8 = 2048
    int b   = bid >> 7;
    int nc  = bid & 127;
    int tid = threadIdx.x;
    int nl  = tid >> 5;
    int lc  = tid & 31;
    int n   = nc * 8 + nl;
    const float4* xb = reinterpret_cast<const float4*>(
        x + ((size_t)(b * C_) * N_ + n) * T_) + lc;
    float4 acc = {0.f, 0.f, 0.f, 0.f};
    #pragma unroll 8
    for (int c = 0; c < C_; ++c) {
        float a = alpha[c];
        float4 v = xb[(size_t)c * (N_ * T_ / 4)];
        acc.x += a * v.x; acc.y += a * v.y; acc.z += a * v.z; acc.w += a * v.w;
    }
    reinterpret_cast<float4*>(k + ((size_t)b * N_ + n) * T_)[lc] = acc;
}

// ---------------------------------------------------------------- kernel 2
__global__ __launch_bounds__(128) void kw_partial2(const float* __restrict__ k,
                                                   const float* __restrict__ W1,
                                                   const float* __restrict__ W2,
                                                   float* __restrict__ p1,
                                                   float* __restrict__ p2) {
    __shared__ float wl[32][20];
    int bid = blockIdx.x;            // b*32 + ch
    int b   = bid >> 5;
    int ch  = bid & 31;
    int n0  = ch * 32;
    int t   = threadIdx.x;
    for (int i = t; i < 32 * 20; i += 128) {
        int nl = i & 31, q = i >> 5;
        wl[nl][q] = (q < 10) ? W1[q * N_ + n0 + nl] : W2[(q - 10) * N_ + n0 + nl];
    }
    __syncthreads();
    float a1[R_] = {}, a2[R_] = {};
    const float* kb = k + ((size_t)b * N_ + n0) * T_ + t;
    #pragma unroll 2
    for (int g = 0; g < 4; ++g) {
        float kv[8];
        #pragma unroll
        for (int j = 0; j < 8; ++j) kv[j] = kb[(g * 8 + j) * T_];
        #pragma unroll
        for (int j = 0; j < 8; ++j) {
            int nl = g * 8 + j;
            #pragma unroll
            for (int r = 0; r < R_; ++r) {
                a1[r] += kv[j] * wl[nl][r];
                a2[r] += kv[j] * wl[nl][10 + r];
            }
        }
    }
    #pragma unroll
    for (int r = 0; r < R_; ++r) {
        size_t o = (((size_t)b * R_ + r) * 32 + ch) * T_ + t;
        p1[o] = a1[r];
        p2[o] = a2[r];
    }
}

// ---------------------------------------------------------------- kernel 3
__global__ __launch_bounds__(128) void scores_softmax3(const float* __restrict__ p1,
                                                       const float* __restrict__ p2,
                                                       __bf16* __restrict__ att) {
    __shared__ __align__(16) float kw1s[T_][12];
    __shared__ __align__(16) float kw2s[T_][12];
    __shared__ float sc[T_][T_ + 1];
    int b = blockIdx.x;
    int t = threadIdx.x;
    #pragma unroll
    for (int r = 0; r < R_; ++r) {
        float s1 = 0.f, s2 = 0.f;
        const float* q1 = p1 + (((size_t)b * R_ + r) * 32) * T_ + t;
        const float* q2 = p2 + (((size_t)b * R_ + r) * 32) * T_ + t;
        #pragma unroll 4
        for (int ch = 0; ch < 32; ++ch) { s1 += q1[ch * T_]; s2 += q2[ch * T_]; }
        kw1s[t][r] = s1; kw2s[t][r] = s2;
    }
    __syncthreads();
    float myw[R_];
    #pragma unroll
    for (int r = 0; r < R_; ++r) myw[r] = kw1s[t][r];
    float mx = -1e30f;
    for (int s = 0; s < T_; ++s) {
        float wv[12];
        const float4* qr = reinterpret_cast<const float4*>(&kw2s[s][0]);
        #pragma unroll
        for (int q = 0; q < 3; ++q) *reinterpret_cast<float4*>(&wv[q * 4]) = qr[q];
        float v = 0.f;
        #pragma unroll
        for (int r = 0; r < R_; ++r) v += myw[r] * wv[r];
        sc[t][s] = v;
        mx = fmaxf(mx, v);
    }
    float sum = 0.f;
    for (int s = 0; s < T_; ++s) {
        float e = __expf(sc[t][s] - mx);
        sc[t][s] = e;
        sum += e;
    }
    float inv = 1.0f / sum;
    __bf16* arow = att + ((size_t)b * T_ + t) * T_;
    for (int s8 = 0; s8 < T_; s8 += 8) {
        bf16x8 hv;
        #pragma unroll
        for (int q = 0; q < 8; ++q) hv[q] = (__bf16)(sc[t][s8 + q] * inv);
        *reinterpret_cast<bf16x8*>(arow + s8) = hv;
    }
}

// ---------------------------------------------------------------- kernel 4
// block = (b,c,sg of 4 slabs), decoded from REVERSED bid. Wave w owns
// n-rows [w*16, w*16+16) of each 64-row slab, all 128 t.
//  per slab: [prefetch regs] -> MFMA -> per-wave LDS transpose (private 8KB,
//  no barrier) -> 1KB-coalesced stores -> barrier -> stage next -> barrier.
__global__ __launch_bounds__(256, 2) void out_gemm8(const float* __restrict__ x,
                                                    const __bf16* __restrict__ att,
                                                    float* __restrict__ out) {
    __shared__ __align__(16) __bf16 attl[T_][T_];    // 32 KB swizzled
    __shared__ __align__(16) __bf16 xstage[64][T_];  // 16 KB swizzled
    __shared__ __align__(16) float  otr[4][16][T_];  // 32 KB, 8KB per wave
    int rbid = 2047 - (int)blockIdx.x;   // reverse: L3-hot x tail first
    int sg  = rbid & 3;
    int c   = (rbid >> 2) & 31;
    int b   = rbid >> 7;
    int tid = threadIdx.x;
    char* attb = (char*)&attl[0][0];
    char* xbb  = (char*)&xstage[0][0];
    size_t base = ((size_t)(b * C_ + c) * N_ + sg * 256) * T_;

    // prologue: att (8 uint4) then slab0 x (8 float4); stage both; barrier
    const uint4* ga = reinterpret_cast<const uint4*>(att + (size_t)b * T_ * T_);
    uint4 ar[8];
    #pragma unroll
    for (int i = 0; i < 8; ++i) ar[i] = ga[i * 256 + tid];
    const float4* gx0 = reinterpret_cast<const float4*>(x + base);
    float4 xr[8];
    #pragma unroll
    for (int j = 0; j < 8; ++j) xr[j] = gx0[j * 256 + tid];
    #pragma unroll
    for (int i = 0; i < 8; ++i) {
        int e = i * 256 + tid, row = e >> 4;
        int bc = ((e & 15) * 16) ^ ((row & 7) << 4);
        *reinterpret_cast<uint4*>(attb + row * 256 + bc) = ar[i];
    }
    #pragma unroll
    for (int j = 0; j < 8; ++j) {
        int e = j * 256 + tid, row = e >> 5;
        bf16x4 hv = {(__bf16)xr[j].x, (__bf16)xr[j].y, (__bf16)xr[j].z, (__bf16)xr[j].w};
        *reinterpret_cast<bf16x4*>(xbb + row * 256 + (((e & 31) * 8) ^ ((row & 7) << 4))) = hv;
    }
    lds_barrier();

    int wave = tid >> 6, lane = tid & 63;
    int r16 = lane & 15, g = lane >> 4;
    int swz = (r16 & 7) << 4;
    char* myo = (char*)&otr[wave][0][0];
    int l32 = lane & 31, lh = lane >> 5;

    #pragma unroll
    for (int i = 0; i < 4; ++i) {
        float4 xn[8];
        if (i < 3) {                 // issue next-slab loads early
            const float4* gxn = reinterpret_cast<const float4*>(
                x + base + ((size_t)(i + 1) * 64) * T_);
            #pragma unroll
            for (int j = 0; j < 8; ++j) xn[j] = gxn[j * 256 + tid];
        }
        // MFMA: A = att rows t (tt*16+r16), B = x rows n (wave*16+r16)
        f32x4 acc[8] = {};
        #pragma unroll
        for (int ks = 0; ks < 4; ++ks) {
            int kc = ks * 64 + g * 16;
            bf16x8 bx = *reinterpret_cast<const bf16x8*>(
                xbb + (wave * 16 + r16) * 256 + (kc ^ swz));
            bf16x8 a[8];
            #pragma unroll
            for (int tt = 0; tt < 8; ++tt)
                a[tt] = *reinterpret_cast<const bf16x8*>(
                    attb + (tt * 16 + r16) * 256 + (kc ^ swz));
            #pragma unroll
            for (int tt = 0; tt < 8; ++tt)
                acc[tt] = __builtin_amdgcn_mfma_f32_16x16x32_bf16(a[tt], bx, acc[tt], 0, 0, 0);
        }
        // per-wave transpose: acc -> private otr (row = r16, no barrier)
        #pragma unroll
        for (int tt = 0; tt < 8; ++tt)
            *reinterpret_cast<f32x4*>(
                myo + r16 * 512 + ((tt * 64 + g * 16) ^ ((r16 & 7) << 4))) = acc[tt];
        asm volatile("s_waitcnt lgkmcnt(0)" ::: "memory");
        // coalesced stores: 2 contiguous rows / instr, 8 instr = 8 KB
        float* orow = out + base + ((size_t)i * 64 + wave * 16) * T_;
        #pragma unroll
        for (int ii = 0; ii < 8; ++ii) {
            int row = ii * 2 + lh;
            f32x4 v = *reinterpret_cast<const f32x4*>(
                myo + row * 512 + ((l32 * 16) ^ ((row & 7) << 4)));
            *reinterpret_cast<f32x4*>(orow + row * T_ + l32 * 4) = v;
        }
        // stage next slab
        if (i < 3) {
            lds_barrier();           // all waves' MFMA(i) reads of xstage done
            #pragma unroll
            for (int j = 0; j < 8; ++j) {
                int e = j * 256 + tid, row = e >> 5;
                bf16x4 hv = {(__bf16)xn[j].x, (__bf16)xn[j].y,
                             (__bf16)xn[j].z, (__bf16)xn[j].w};
                *reinterpret_cast<bf16x4*>(
                    xbb + row * 256 + (((e & 31) * 8) ^ ((row & 7) << 4))) = hv;
            }
            lds_barrier();
        }
    }
}

// ----------------------------------------------------------------
extern "C" void kernel_launch(void* const* d_in, const int* in_sizes, int n_in,
                              void* d_out, int out_size, void* d_ws, size_t ws_size,
                              hipStream_t stream) {
    const float* x     = (const float*)d_in[0];
    const float* W1    = (const float*)d_in[1];
    const float* W2    = (const float*)d_in[2];
    const float* alpha = (const float*)d_in[3];
    float* out = (float*)d_out;

    const size_t KSZ = (size_t)B_ * N_ * T_;            // f32
    const size_t PSZ = (size_t)B_ * R_ * 32 * T_;       // f32
    float* k    = (float*)d_ws;
    float* p1   = k + KSZ;
    float* p2   = p1 + PSZ;
    __bf16* att = (__bf16*)(p2 + PSZ);                  // [b][t][s]

    k_reduce_c     <<<dim3(B_ * (N_ / 8)), dim3(256), 0, stream>>>(x, alpha, k);
    kw_partial2    <<<dim3(B_ * 32),       dim3(128), 0, stream>>>(k, W1, W2, p1, p2);
    scores_softmax3<<<dim3(B_),            dim3(128), 0, stream>>>(p1, p2, att);
    out_gemm8      <<<dim3(B_ * C_ * 4),   dim3(256), 0, stream>>>(x, att, out);
}

// Round 13
// 199.618 us; speedup vs baseline: 1.5065x; 1.0063x over previous
//
#include <hip/hip_runtime.h>
#include <hip/hip_bf16.h>

// TAttention: B=16, C=32, N=1024, T=128, R=10
//  K1 k_reduce_c : k[b,n,t] = sum_c alpha[c]*x[b,c,n,t]    (256 MB read, BW)
//  K2 kw_partial2: p_w[b][r][ch32][t] partials             (8 MB, fast)
//  K3 scores_softmax3: partial-reduce + scores + softmax -> att bf16 (tiny)
//  K4 out_gemm4nt: EXACT R7 kernel (best known, 186us total) + ONE change:
//     non-temporal x loads + non-temporal out stores (via ext_vector f32x4 —
//     the builtin rejects HIP_vector_type). Theory: K4's 50/50 read/write mix
//     thrashes the 4MB/XCD L2; nt bypasses L2 allocation for the streams.
// Dead theories (measured): barrier drain (R7), store scatter (R11),
// occupancy (R10: 51% + all-idle), LDS conflicts (0), per-block softmax (R4).

#define B_ 16
#define C_ 32
#define N_ 1024
#define T_ 128
#define R_ 10

typedef __bf16 bf16x8 __attribute__((ext_vector_type(8)));
typedef __bf16 bf16x4 __attribute__((ext_vector_type(4)));
typedef float f32x4 __attribute__((ext_vector_type(4)));

__device__ __forceinline__ void lds_barrier() {
    asm volatile("s_waitcnt lgkmcnt(0)" ::: "memory");
    __builtin_amdgcn_s_barrier();
    asm volatile("" ::: "memory");
}

// ---------------------------------------------------------------- kernel 1
__global__ __launch_bounds__(256) void k_reduce_c(const float* __restrict__ x,
                                                  const float* __restrict__ alpha,
                                                  float* __restrict__ k) {
    int bid = blockIdx.x;            // B * N/8 = 2048
    int b   = bid >> 7;
    int nc  = bid & 127;
    int tid = threadIdx.x;
    int nl  = tid >> 5;
    int lc  = tid & 31;
    int n   = nc * 8 + nl;
    const float4* xb = reinterpret_cast<const float4*>(
        x + ((size_t)(b * C_) * N_ + n) * T_) + lc;
    float4 acc = {0.f, 0.f, 0.f, 0.f};
    #pragma unroll 8
    for (int c = 0; c < C_; ++c) {
        float a = alpha[c];
        float4 v = xb[(size_t)c * (N_ * T_ / 4)];
        acc.x += a * v.x; acc.y += a * v.y; acc.z += a * v.z; acc.w += a * v.w;
    }
    reinterpret_cast<float4*>(k + ((size_t)b * N_ + n) * T_)[lc] = acc;
}

// ---------------------------------------------------------------- kernel 2
__global__ __launch_bounds__(128) void kw_partial2(const float* __restrict__ k,
                                                   const float* __restrict__ W1,
                                                   const float* __restrict__ W2,
                                                   float* __restrict__ p1,
                                                   float* __restrict__ p2) {
    __shared__ float wl[32][20];
    int bid = blockIdx.x;            // b*32 + ch
    int b   = bid >> 5;
    int ch  = bid & 31;
    int n0  = ch * 32;
    int t   = threadIdx.x;
    for (int i = t; i < 32 * 20; i += 128) {
        int nl = i & 31, q = i >> 5;
        wl[nl][q] = (q < 10) ? W1[q * N_ + n0 + nl] : W2[(q - 10) * N_ + n0 + nl];
    }
    __syncthreads();
    float a1[R_] = {}, a2[R_] = {};
    const float* kb = k + ((size_t)b * N_ + n0) * T_ + t;
    #pragma unroll 2
    for (int g = 0; g < 4; ++g) {
        float kv[8];
        #pragma unroll
        for (int j = 0; j < 8; ++j) kv[j] = kb[(g * 8 + j) * T_];
        #pragma unroll
        for (int j = 0; j < 8; ++j) {
            int nl = g * 8 + j;
            #pragma unroll
            for (int r = 0; r < R_; ++r) {
                a1[r] += kv[j] * wl[nl][r];
                a2[r] += kv[j] * wl[nl][10 + r];
            }
        }
    }
    #pragma unroll
    for (int r = 0; r < R_; ++r) {
        size_t o = (((size_t)b * R_ + r) * 32 + ch) * T_ + t;
        p1[o] = a1[r];
        p2[o] = a2[r];
    }
}

// ---------------------------------------------------------------- kernel 3
__global__ __launch_bounds__(128) void scores_softmax3(const float* __restrict__ p1,
                                                       const float* __restrict__ p2,
                                                       __bf16* __restrict__ att) {
    __shared__ __align__(16) float kw1s[T_][12];
    __shared__ __align__(16) float kw2s[T_][12];
    __shared__ float sc[T_][T_ + 1];
    int b = blockIdx.x;
    int t = threadIdx.x;
    #pragma unroll
    for (int r = 0; r < R_; ++r) {
        float s1 = 0.f, s2 = 0.f;
        const float* q1 = p1 + (((size_t)b * R_ + r) * 32) * T_ + t;
        const float* q2 = p2 + (((size_t)b * R_ + r) * 32) * T_ + t;
        #pragma unroll 4
        for (int ch = 0; ch < 32; ++ch) { s1 += q1[ch * T_]; s2 += q2[ch * T_]; }
        kw1s[t][r] = s1; kw2s[t][r] = s2;
    }
    __syncthreads();
    float myw[R_];
    #pragma unroll
    for (int r = 0; r < R_; ++r) myw[r] = kw1s[t][r];
    float mx = -1e30f;
    for (int s = 0; s < T_; ++s) {
        float wv[12];
        const float4* qr = reinterpret_cast<const float4*>(&kw2s[s][0]);
        #pragma unroll
        for (int q = 0; q < 3; ++q) *reinterpret_cast<float4*>(&wv[q * 4]) = qr[q];
        float v = 0.f;
        #pragma unroll
        for (int r = 0; r < R_; ++r) v += myw[r] * wv[r];
        sc[t][s] = v;
        mx = fmaxf(mx, v);
    }
    float sum = 0.f;
    for (int s = 0; s < T_; ++s) {
        float e = __expf(sc[t][s] - mx);
        sc[t][s] = e;
        sum += e;
    }
    float inv = 1.0f / sum;
    __bf16* arow = att + ((size_t)b * T_ + t) * T_;
    for (int s8 = 0; s8 < T_; s8 += 8) {
        bf16x8 hv;
        #pragma unroll
        for (int q = 0; q < 8; ++q) hv[q] = (__bf16)(sc[t][s8 + q] * inv);
        *reinterpret_cast<bf16x8*>(arow + s8) = hv;
    }
}

// ---------------------------------------------------------------- kernel 4
// R7 kernel verbatim except: x loads nontemporal, out stores nontemporal.
__global__ __launch_bounds__(256, 2) void out_gemm4nt(const float* __restrict__ x,
                                                      const __bf16* __restrict__ att,
                                                      float* __restrict__ out) {
    __shared__ __align__(16) __bf16 attl[T_][T_];      // 32 KB swizzled
    __shared__ __align__(16) __bf16 xsl[2][64][T_];    // 2 x 16 KB swizzled
    int bid = blockIdx.x;            // b*128 + c*4 + sg
    int sg  = bid & 3;
    int c   = (bid >> 2) & 31;
    int b   = bid >> 7;
    int tid = threadIdx.x;
    char* attb = (char*)&attl[0][0];
    size_t slab0 = ((size_t)(b * C_ + c) * N_ + (sg * 4) * 64) * T_;

    // ---- prologue: att + slab0, staged, one barrier
    const uint4* ga = reinterpret_cast<const uint4*>(att + (size_t)b * T_ * T_);
    uint4 ar[8];
    #pragma unroll
    for (int i = 0; i < 8; ++i) ar[i] = ga[i * 256 + tid];
    const f32x4* gx0 = reinterpret_cast<const f32x4*>(x + slab0);
    f32x4 xr[8];
    #pragma unroll
    for (int j = 0; j < 8; ++j) xr[j] = __builtin_nontemporal_load(&gx0[j * 256 + tid]);
    #pragma unroll
    for (int i = 0; i < 8; ++i) {
        int e = i * 256 + tid, row = e >> 4;
        int bc = ((e & 15) * 16) ^ ((row & 7) << 4);
        *reinterpret_cast<uint4*>(attb + row * 256 + bc) = ar[i];
    }
    {
        char* xb0 = (char*)&xsl[0][0][0];
        #pragma unroll
        for (int j = 0; j < 8; ++j) {
            int e = j * 256 + tid, row = e >> 5;
            bf16x4 hv = {(__bf16)xr[j][0], (__bf16)xr[j][1], (__bf16)xr[j][2], (__bf16)xr[j][3]};
            *reinterpret_cast<bf16x4*>(xb0 + row * 256 + (((e & 31) * 8) ^ ((row & 7) << 4))) = hv;
        }
    }
    lds_barrier();

    int wave = tid >> 6, lane = tid & 63;
    int r16 = lane & 15, g = lane >> 4;
    int wt = wave & 1, wn = wave >> 1;
    int swz = (r16 & 7) << 4;

    #pragma unroll
    for (int i = 0; i < 4; ++i) {
        // issue next-slab loads (in flight through MFMA+stores)
        f32x4 xn[8];
        if (i < 3) {
            const f32x4* gxn = reinterpret_cast<const f32x4*>(
                x + slab0 + ((size_t)(i + 1) * 64) * T_);
            #pragma unroll
            for (int j = 0; j < 8; ++j) xn[j] = __builtin_nontemporal_load(&gxn[j * 256 + tid]);
        }
        // MFMA on current slab from buf i&1 (verified R2 core)
        const char* xbb = (const char*)&xsl[i & 1][0][0];
        f32x4 acc[2][4] = {};
        #pragma unroll
        for (int ks = 0; ks < 4; ++ks) {
            int kc = ks * 64 + g * 16;
            bf16x8 a[4], bx[2];
            #pragma unroll
            for (int tt = 0; tt < 4; ++tt)
                a[tt] = *reinterpret_cast<const bf16x8*>(
                    attb + (wt * 64 + tt * 16 + r16) * 256 + (kc ^ swz));
            #pragma unroll
            for (int nn = 0; nn < 2; ++nn)
                bx[nn] = *reinterpret_cast<const bf16x8*>(
                    xbb + (wn * 32 + nn * 16 + r16) * 256 + (kc ^ swz));
            #pragma unroll
            for (int nn = 0; nn < 2; ++nn)
                #pragma unroll
                for (int tt = 0; tt < 4; ++tt)
                    acc[nn][tt] = __builtin_amdgcn_mfma_f32_16x16x32_bf16(
                        a[tt], bx[nn], acc[nn][tt], 0, 0, 0);
        }
        // nontemporal stores (streaming; don't allocate in L2)
        float* o = out + slab0 + ((size_t)i * 64) * T_;
        #pragma unroll
        for (int nn = 0; nn < 2; ++nn) {
            int n_l = wn * 32 + nn * 16 + r16;
            #pragma unroll
            for (int tt = 0; tt < 4; ++tt)
                __builtin_nontemporal_store(acc[nn][tt],
                    reinterpret_cast<f32x4*>(
                        o + (size_t)n_l * T_ + (wt * 64 + tt * 16 + g * 4)));
        }
        // write next slab into the other buffer; one barrier per slab
        if (i < 3) {
            char* xw = (char*)&xsl[(i + 1) & 1][0][0];
            #pragma unroll
            for (int j = 0; j < 8; ++j) {
                int e = j * 256 + tid, row = e >> 5;
                bf16x4 hv = {(__bf16)xn[j][0], (__bf16)xn[j][1],
                             (__bf16)xn[j][2], (__bf16)xn[j][3]};
                *reinterpret_cast<bf16x4*>(
                    xw + row * 256 + (((e & 31) * 8) ^ ((row & 7) << 4))) = hv;
            }
            lds_barrier();
        }
    }
}

// ----------------------------------------------------------------
extern "C" void kernel_launch(void* const* d_in, const int* in_sizes, int n_in,
                              void* d_out, int out_size, void* d_ws, size_t ws_size,
                              hipStream_t stream) {
    const float* x     = (const float*)d_in[0];
    const float* W1    = (const float*)d_in[1];
    const float* W2    = (const float*)d_in[2];
    const float* alpha = (const float*)d_in[3];
    float* out = (float*)d_out;

    const size_t KSZ = (size_t)B_ * N_ * T_;            // f32
    const size_t PSZ = (size_t)B_ * R_ * 32 * T_;       // f32
    float* k    = (float*)d_ws;
    float* p1   = k + KSZ;
    float* p2   = p1 + PSZ;
    __bf16* att = (__bf16*)(p2 + PSZ);                  // [b][t][s]

    k_reduce_c     <<<dim3(B_ * (N_ / 8)), dim3(256), 0, stream>>>(x, alpha, k);
    kw_partial2    <<<dim3(B_ * 32),       dim3(128), 0, stream>>>(k, W1, W2, p1, p2);
    scores_softmax3<<<dim3(B_),            dim3(128), 0, stream>>>(p1, p2, att);
    out_gemm4nt    <<<dim3(B_ * C_ * 4),   dim3(256), 0, stream>>>(x, att, out);
}